// Round 5
// baseline (770.242 us; speedup 1.0000x reference)
//
#include <hip/hip_runtime.h>

#define BATCH  512
#define SEQ    1024
#define NT     64
#define CHUNK  64
#define NCHUNK (SEQ / CHUNK)

typedef _Float16 half2_t __attribute__((ext_vector_type(2)));

__device__ __forceinline__ float readlane_f(float v, int lane) {
    return __uint_as_float(__builtin_amdgcn_readlane(__float_as_uint(v), lane));
}

__device__ __forceinline__ int pkrtz_bits(float a, float b) {
    auto pk = __builtin_amdgcn_cvt_pkrtz(a, b);
    return __builtin_bit_cast(int, pk);
}

__device__ __forceinline__ half2_t bc_h2(int v) { return __builtin_bit_cast(half2_t, v); }

__device__ __forceinline__ float fdot2(int a_bits, int b_bits, float c) {
#if __has_builtin(__builtin_amdgcn_fdot2)
    return __builtin_amdgcn_fdot2(bc_h2(a_bits), bc_h2(b_bits), c, false);
#else
    half2_t a = bc_h2(a_bits), b = bc_h2(b_bits);
    return fmaf((float)a.y, (float)b.y, fmaf((float)a.x, (float)b.x, c));
#endif
}

#define GLDS16(gsrc, ldst) \
    __builtin_amdgcn_global_load_lds( \
        (const __attribute__((address_space(1))) unsigned int*)(gsrc), \
        (__attribute__((address_space(3))) unsigned int*)(ldst), 16, 0, 0)
#define GLDS4(gsrc, ldst) \
    __builtin_amdgcn_global_load_lds( \
        (const __attribute__((address_space(1))) unsigned int*)(gsrc), \
        (__attribute__((address_space(3))) unsigned int*)(ldst), 4, 0, 0)

// One wave per TWO batches: two independent dp recurrences interleaved in the
// same loop body. Rationale (round-4 post-mortem): 860 cyc/step with only 190
// issuing => ~670 cyc of exposed serial-chain stalls and no co-resident wave
// to fill them (1 wave/SIMD). The second chain provides in-wave ILP that fills
// exp/log latency, readlane hazards, and dot-chain depth. E (32 packed-f16
// pairs) is shared by both chains — no duplication. Emissions/masks staged via
// double-buffered LDS DMA (global_load_lds), single wave => no barriers, only
// s_waitcnt vmcnt(N).
__global__ __launch_bounds__(64, 1) void crf_kernel(
        const float* __restrict__ emis,
        const int*   __restrict__ tags,
        const float* __restrict__ mask,
        const float* __restrict__ trans,
        float*       __restrict__ out)
{
    const int b0 = 2 * blockIdx.x;
    const int b1 = b0 + 1;
    const int j = threadIdx.x;

    __shared__ float lds_e[2][2][CHUNK * NT];   // [buf][batch] 4 x 16 KB
    __shared__ float lds_m[2][2][CHUNK];        // [buf][batch]

    // ---- E pairs, straight-line init (shared by both batches) ----
    int Eh[32];
#define EINIT(P) { \
        float ea  = __expf(trans[(2*(P)+0)*NT + j]); \
        float eb2 = __expf(trans[(2*(P)+1)*NT + j]); \
        int bits = pkrtz_bits(ea, eb2); \
        asm volatile("" : "+v"(bits)); \
        Eh[P] = bits; }
#define EINIT4(P) EINIT(P) EINIT((P)+1) EINIT((P)+2) EINIT((P)+3)
    EINIT4(0) EINIT4(4) EINIT4(8) EINIT4(12)
    EINIT4(16) EINIT4(20) EINIT4(24) EINIT4(28)

    const float* eb0 = emis + (size_t)b0 * SEQ * NT;
    const float* eb1 = emis + (size_t)b1 * SEQ * NT;
    const float* mb0 = mask + (size_t)b0 * SEQ;
    const float* mb1 = mask + (size_t)b1 * SEQ;

    // ---- stage chunk 0 into buffer 0 (34 DMA ops) ----
    {
        #pragma unroll
        for (int k = 0; k < 16; ++k) {
            GLDS16(eb0 + k * 256 + j * 4, &lds_e[0][0][k * 256]);
            GLDS16(eb1 + k * 256 + j * 4, &lds_e[0][1][k * 256]);
        }
        GLDS4(mb0 + j, &lds_m[0][0][0]);
        GLDS4(mb1 + j, &lds_m[0][1][0]);
    }

    const float LOG16 = 2.7725887222397811f;
    float dp0 = 0.0f, dp1 = 0.0f;

    for (int c = 0; c < NCHUNK; ++c) {
        const int buf = c & 1;
        if (c + 1 < NCHUNK) {
            const float* s0g = eb0 + (c + 1) * CHUNK * NT;
            const float* s1g = eb1 + (c + 1) * CHUNK * NT;
            #pragma unroll
            for (int k = 0; k < 16; ++k) {
                GLDS16(s0g + k * 256 + j * 4, &lds_e[buf ^ 1][0][k * 256]);
                GLDS16(s1g + k * 256 + j * 4, &lds_e[buf ^ 1][1][k * 256]);
            }
            GLDS4(mb0 + (c + 1) * CHUNK + j, &lds_m[buf ^ 1][0][0]);
            GLDS4(mb1 + (c + 1) * CHUNK + j, &lds_m[buf ^ 1][1][0]);
            asm volatile("s_waitcnt vmcnt(34)" ::: "memory");  // chunk c landed
        } else {
            asm volatile("s_waitcnt vmcnt(0)" ::: "memory");
        }

        const float* ep0 = &lds_e[buf][0][0];
        const float* ep1 = &lds_e[buf][1][0];
        const float* mp0 = &lds_m[buf][0][0];
        const float* mp1 = &lds_m[buf][1][0];

        #pragma unroll 2
        for (int tt = 0; tt < CHUNK; ++tt) {
            float e0 = ep0[tt * NT + j];
            float e1 = ep1[tt * NT + j];
            float mk0 = mp0[tt];
            float mk1 = mp1[tt];

            float msh0 = readlane_f(dp0, 0) + LOG16;
            float msh1 = readlane_f(dp1, 0) + LOG16;
            float w0 = __expf(dp0 - msh0);
            float w1 = __expf(dp1 - msh1);

            int wb0 = __builtin_bit_cast(int, w0);
            int wb1 = __builtin_bit_cast(int, w1);
#if __has_builtin(__builtin_amdgcn_mov_dpp)
            float wn0 = __builtin_bit_cast(float, __builtin_amdgcn_mov_dpp(wb0, 0xB1, 0xF, 0xF, true));
            float wn1 = __builtin_bit_cast(float, __builtin_amdgcn_mov_dpp(wb1, 0xB1, 0xF, 0xF, true));
#else
            float wn0 = __shfl_xor(w0, 1, 64);
            float wn1 = __shfl_xor(w1, 1, 64);
#endif
            int whb0 = pkrtz_bits(w0, wn0);
            int whb1 = pkrtz_bits(w1, wn1);

            float s00 = 0.f, s01 = 0.f, s02 = 0.f, s03 = 0.f;
            float s10 = 0.f, s11 = 0.f, s12 = 0.f, s13 = 0.f;
#define MV4D(P) \
            s00 = fdot2(__builtin_amdgcn_readlane(whb0, 2*((P)+0)), Eh[(P)+0], s00); \
            s10 = fdot2(__builtin_amdgcn_readlane(whb1, 2*((P)+0)), Eh[(P)+0], s10); \
            s01 = fdot2(__builtin_amdgcn_readlane(whb0, 2*((P)+1)), Eh[(P)+1], s01); \
            s11 = fdot2(__builtin_amdgcn_readlane(whb1, 2*((P)+1)), Eh[(P)+1], s11); \
            s02 = fdot2(__builtin_amdgcn_readlane(whb0, 2*((P)+2)), Eh[(P)+2], s02); \
            s12 = fdot2(__builtin_amdgcn_readlane(whb1, 2*((P)+2)), Eh[(P)+2], s12); \
            s03 = fdot2(__builtin_amdgcn_readlane(whb0, 2*((P)+3)), Eh[(P)+3], s03); \
            s13 = fdot2(__builtin_amdgcn_readlane(whb1, 2*((P)+3)), Eh[(P)+3], s13);
            MV4D(0) MV4D(4) MV4D(8) MV4D(12) MV4D(16) MV4D(20) MV4D(24) MV4D(28)
            float S0 = (s00 + s01) + (s02 + s03);
            float S1 = (s10 + s11) + (s12 + s13);

            float dpn0 = msh0 + __logf(S0) + e0;
            float dpn1 = msh1 + __logf(S1) + e1;
            dp0 = fmaf(mk0, dpn0 - dp0, dp0);
            dp1 = fmaf(mk1, dpn1 - dp1, dp1);
        }
    }

    // ---- z = logsumexp(dp) for both batches ----
    float m0 = dp0, m1 = dp1;
    #pragma unroll
    for (int off = 32; off >= 1; off >>= 1) {
        m0 = fmaxf(m0, __shfl_xor(m0, off, 64));
        m1 = fmaxf(m1, __shfl_xor(m1, off, 64));
    }
    float se0 = __expf(dp0 - m0), se1 = __expf(dp1 - m1);
    #pragma unroll
    for (int off = 32; off >= 1; off >>= 1) {
        se0 += __shfl_xor(se0, off, 64);
        se1 += __shfl_xor(se1, off, 64);
    }
    float z0 = m0 + __logf(se0);
    float z1 = m1 + __logf(se1);

    // ---- gold scores ----
    const int* tb0 = tags + b0 * SEQ;
    const int* tb1 = tags + b1 * SEQ;
    float acc0 = 0.0f, acc1 = 0.0f;
    for (int s = 1 + j; s < SEQ; s += 64) {
        int tc0 = tb0[s], tp0 = tb0[s - 1];
        int tc1 = tb1[s], tp1 = tb1[s - 1];
        acc0 += (eb0[s * NT + tc0] + trans[tp0 * NT + tc0]) * mb0[s];
        acc1 += (eb1[s * NT + tc1] + trans[tp1 * NT + tc1]) * mb1[s];
    }
    #pragma unroll
    for (int off = 32; off >= 1; off >>= 1) {
        acc0 += __shfl_xor(acc0, off, 64);
        acc1 += __shfl_xor(acc1, off, 64);
    }

    if (j == 0)
        atomicAdd(out, ((acc0 - z0) + (acc1 - z1)) * (1.0f / BATCH));
}

__global__ void zero_kernel(float* out) { if (threadIdx.x == 0) out[0] = 0.0f; }

extern "C" void kernel_launch(void* const* d_in, const int* in_sizes, int n_in,
                              void* d_out, int out_size, void* d_ws, size_t ws_size,
                              hipStream_t stream) {
    const float* emis  = (const float*)d_in[0];
    const int*   tags  = (const int*)d_in[1];
    const float* mask  = (const float*)d_in[2];
    const float* trans = (const float*)d_in[3];
    float* out = (float*)d_out;

    zero_kernel<<<1, 64, 0, stream>>>(out);
    crf_kernel<<<BATCH / 2, 64, 0, stream>>>(emis, tags, mask, trans, out);
}

// Round 6
// 429.696 us; speedup vs baseline: 1.7925x; 1.7925x over previous
//
#include <hip/hip_runtime.h>

#define BATCH  512
#define SEQ    1024
#define NT     64
#define CHUNK  64
#define NCHUNK (SEQ / CHUNK)

typedef _Float16 half2_t __attribute__((ext_vector_type(2)));
typedef int int4v __attribute__((ext_vector_type(4)));

__device__ __forceinline__ int pkrtz_bits(float a, float b) {
    auto pk = __builtin_amdgcn_cvt_pkrtz(a, b);
    return __builtin_bit_cast(int, pk);
}

__device__ __forceinline__ half2_t bc_h2(int v) { return __builtin_bit_cast(half2_t, v); }

__device__ __forceinline__ float fdot2(int a_bits, int b_bits, float c) {
#if __has_builtin(__builtin_amdgcn_fdot2)
    return __builtin_amdgcn_fdot2(bc_h2(a_bits), bc_h2(b_bits), c, false);
#else
    half2_t a = bc_h2(a_bits), b = bc_h2(b_bits);
    return fmaf((float)a.y, (float)b.y, fmaf((float)a.x, (float)b.x, c));
#endif
}

#define GLDS16(gsrc, ldst) \
    __builtin_amdgcn_global_load_lds( \
        (const __attribute__((address_space(1))) unsigned int*)(gsrc), \
        (__attribute__((address_space(3))) unsigned int*)(ldst), 16, 0, 0)
#define GLDS4(gsrc, ldst) \
    __builtin_amdgcn_global_load_lds( \
        (const __attribute__((address_space(1))) unsigned int*)(gsrc), \
        (__attribute__((address_space(3))) unsigned int*)(ldst), 4, 0, 0)

// One wave per batch (512 waves). ZERO v_readlane in the hot loop (round-5
// post-mortem: readlane ≈ 18 cyc issue-blocking each; 33/step explains the
// ~860 cyc/step plateau). Broadcast of w is done through LDS: lane j writes
// its f16 w (ds_write_b16, 128 B region), then 8x ds_read_b128 at wave-uniform
// addresses (same-address broadcast, conflict-free) deliver all 32 packed
// pairs as VGPR operands for v_dot2_f32_f16 — no SGPR hazards. Proxy max via
// ds_bpermute(lane 0). Same-wave LDS ops execute in order -> no barrier.
// Emissions/mask staged per 64-step chunk via double-buffered global_load_lds.
__global__ __launch_bounds__(64, 1) void crf_kernel(
        const float* __restrict__ emis,
        const int*   __restrict__ tags,
        const float* __restrict__ mask,
        const float* __restrict__ trans,
        float*       __restrict__ out)
{
    const int b = blockIdx.x;
    const int j = threadIdx.x;

    __shared__ float lds_e[2][CHUNK * NT];        // 2 x 16 KB
    __shared__ float lds_m[2][CHUNK];             // 2 x 256 B
    __shared__ __align__(16) _Float16 wl[NT];     // 128 B w-broadcast buffer

    // ---- E pairs in VGPRs: Eh[p] = (exp(T[2p][j]), exp(T[2p+1][j])) ----
    int Eh[32];
#define EINIT(P) { \
        float ea  = __expf(trans[(2*(P)+0)*NT + j]); \
        float eb2 = __expf(trans[(2*(P)+1)*NT + j]); \
        int bits = pkrtz_bits(ea, eb2); \
        asm volatile("" : "+v"(bits)); \
        Eh[P] = bits; }
#define EINIT4(P) EINIT(P) EINIT((P)+1) EINIT((P)+2) EINIT((P)+3)
    EINIT4(0) EINIT4(4) EINIT4(8) EINIT4(12)
    EINIT4(16) EINIT4(20) EINIT4(24) EINIT4(28)

    const float* eb = emis + (size_t)b * SEQ * NT;
    const float* mb = mask + (size_t)b * SEQ;

    // ---- stage chunk 0 into buffer 0 (17 DMA ops) ----
    {
        #pragma unroll
        for (int k = 0; k < 16; ++k)
            GLDS16(eb + k * 256 + j * 4, &lds_e[0][k * 256]);
        GLDS4(mb + j, &lds_m[0][0]);
    }

    const float LOG16 = 2.7725887222397811f;
    float dp = 0.0f;

    for (int c = 0; c < NCHUNK; ++c) {
        const int buf = c & 1;
        if (c + 1 < NCHUNK) {
            const float* src = eb + (c + 1) * CHUNK * NT;
            #pragma unroll
            for (int k = 0; k < 16; ++k)
                GLDS16(src + k * 256 + j * 4, &lds_e[buf ^ 1][k * 256]);
            GLDS4(mb + (c + 1) * CHUNK + j, &lds_m[buf ^ 1][0]);
            asm volatile("s_waitcnt vmcnt(17)" ::: "memory");  // chunk c landed
        } else {
            asm volatile("s_waitcnt vmcnt(0)" ::: "memory");
        }

        const float* ep = &lds_e[buf][0];
        const float* mp = &lds_m[buf][0];
        const int4v* wp = (const int4v*)wl;

        #pragma unroll 2
        for (int tt = 0; tt < CHUNK; ++tt) {
            float e_t = ep[tt * NT + j];   // ds_read_b32 (used late -> hidden)
            float mk  = mp[tt];            // uniform-addr ds_read_b32 broadcast

            // proxy max: lane 0's dp via ds_bpermute (no readlane in loop)
            int mshb = __builtin_amdgcn_ds_bpermute(0, __builtin_bit_cast(int, dp));
            float msh = __builtin_bit_cast(float, mshb) + LOG16;
            float w = __expf(dp - msh);    // spread(dp) <= ~11.2 -> f16-safe

            wl[j] = (_Float16)w;           // ds_write_b16; in-order same-wave

            // 8x ds_read_b128 broadcast -> 32 packed pairs in VGPRs
            float s0 = 0.f, s1 = 0.f, s2 = 0.f, s3 = 0.f;
#define MVQ(K) { int4v q = wp[K]; \
            s0 = fdot2(q.x, Eh[4*(K)+0], s0); \
            s1 = fdot2(q.y, Eh[4*(K)+1], s1); \
            s2 = fdot2(q.z, Eh[4*(K)+2], s2); \
            s3 = fdot2(q.w, Eh[4*(K)+3], s3); }
            MVQ(0) MVQ(1) MVQ(2) MVQ(3) MVQ(4) MVQ(5) MVQ(6) MVQ(7)
            float S = (s0 + s1) + (s2 + s3);

            float dpn = msh + __logf(S) + e_t;
            dp = fmaf(mk, dpn - dp, dp);
        }
    }

    // ---- z_b = logsumexp_j dp[j] (epilogue: shuffles fine here) ----
    float m = dp;
    #pragma unroll
    for (int off = 32; off >= 1; off >>= 1)
        m = fmaxf(m, __shfl_xor(m, off, 64));
    float se = __expf(dp - m);
    #pragma unroll
    for (int off = 32; off >= 1; off >>= 1)
        se += __shfl_xor(se, off, 64);
    float z = m + __logf(se);

    // ---- gold score ----
    const int* tb = tags + b * SEQ;
    float acc = 0.0f;
    for (int s = 1 + j; s < SEQ; s += 64) {
        int tc = tb[s];
        int tp = tb[s - 1];
        acc += (eb[s * NT + tc] + trans[tp * NT + tc]) * mb[s];
    }
    #pragma unroll
    for (int off = 32; off >= 1; off >>= 1)
        acc += __shfl_xor(acc, off, 64);

    if (j == 0)
        atomicAdd(out, (acc - z) * (1.0f / BATCH));
}

__global__ void zero_kernel(float* out) { if (threadIdx.x == 0) out[0] = 0.0f; }

extern "C" void kernel_launch(void* const* d_in, const int* in_sizes, int n_in,
                              void* d_out, int out_size, void* d_ws, size_t ws_size,
                              hipStream_t stream) {
    const float* emis  = (const float*)d_in[0];
    const int*   tags  = (const int*)d_in[1];
    const float* mask  = (const float*)d_in[2];
    const float* trans = (const float*)d_in[3];
    float* out = (float*)d_out;

    zero_kernel<<<1, 64, 0, stream>>>(out);
    crf_kernel<<<BATCH, 64, 0, stream>>>(emis, tags, mask, trans, out);
}